// Round 2
// baseline (181.102 us; speedup 1.0000x reference)
//
#include <hip/hip_runtime.h>
#include <stdint.h>

typedef __attribute__((ext_vector_type(8))) short short8;
typedef __attribute__((ext_vector_type(4))) short short4v;
typedef __attribute__((ext_vector_type(4))) float f32x4;
typedef __attribute__((ext_vector_type(4))) unsigned short ushort4v;

#define AS1(p) ((const __attribute__((address_space(1))) void*)(p))
#define AS3(p) ((__attribute__((address_space(3))) void*)(p))

__device__ __forceinline__ void gload_lds16(const void* g, void* l) {
  __builtin_amdgcn_global_load_lds(AS1(g), AS3(l), 16, 0, 0);
}

__device__ __forceinline__ unsigned short f2bf(float f) {
  union { float f; uint32_t u; } x; x.f = f;
  uint32_t r = x.u + 0x7FFFu + ((x.u >> 16) & 1u);
  return (unsigned short)(r >> 16);
}

// ---------------- cast kernels ----------------
__global__ void cast_x_k(const float* __restrict__ in, short* __restrict__ out) {
  int i = blockIdx.x * 256 + threadIdx.x;           // float4 index
  float4 v = ((const float4*)in)[i];
  short4v o;
  o[0] = (short)f2bf(v.x); o[1] = (short)f2bf(v.y);
  o[2] = (short)f2bf(v.z); o[3] = (short)f2bf(v.w);
  ((short4v*)out)[i] = o;
}

__global__ void cast_wqkv_k(const float* __restrict__ wq, const float* __restrict__ wk,
                            const float* __restrict__ wv, short* __restrict__ out) {
  int i = blockIdx.x * 256 + threadIdx.x;           // float4 index, 0..786431
  int e = i * 4;
  const float* src = (e < (1 << 20)) ? (wq + e)
                   : (e < (2 << 20)) ? (wk + (e - (1 << 20)))
                                     : (wv + (e - (2 << 20)));
  float4 v = *(const float4*)src;
  short4v o;
  o[0] = (short)f2bf(v.x); o[1] = (short)f2bf(v.y);
  o[2] = (short)f2bf(v.z); o[3] = (short)f2bf(v.w);
  ((short4v*)out)[i] = o;
}

__global__ void cast_wo_k(const float* __restrict__ wo, short* __restrict__ out) {
  int i = blockIdx.x * 256 + threadIdx.x;           // 0..262143
  int o4 = i * 4;
  int d = o4 >> 10, c = o4 & 1023;
  const float* s = wo + ((c >> 6) << 16) + (d << 6) + (c & 63);
  float4 v = *(const float4*)s;
  short4v o;
  o[0] = (short)f2bf(v.x); o[1] = (short)f2bf(v.y);
  o[2] = (short)f2bf(v.z); o[3] = (short)f2bf(v.w);
  ((short4v*)out)[i] = o;
}

__global__ void bias_k(const float* __restrict__ bq, const float* __restrict__ bk,
                       const float* __restrict__ bv, float* __restrict__ out) {
  int i = blockIdx.x * 256 + threadIdx.x;           // 0..3071
  out[i] = (i < 1024) ? bq[i] : (i < 2048) ? bk[i - 1024] : bv[i - 2048];
}

// ---------------- GEMM: C[M,N] = A[M,K] * B^T (B stored [N][K]) + bias ----------------
// EPI=0: bf16 out, ldc=3072, scale cols<1024 by 1/8 (q pre-scale)
// EPI=1: fp32 out, ldc=1024
template <int EPI>
__global__ __launch_bounds__(256) void gemm_bt(const short* __restrict__ A,
                                               const short* __restrict__ Bm,
                                               const float* __restrict__ bias,
                                               void* __restrict__ Cout, int K, int ldc) {
  __shared__ short As[128 * 32];
  __shared__ short Bs[128 * 32];
  const int t = threadIdx.x;
  const int l = t & 63, w = t >> 6;
  const int wr = w >> 1, wc = w & 1;
  const int q = l & 15, g = l >> 4;
  const long brow = (long)blockIdx.y * 128;
  const long bcol = (long)blockIdx.x * 128;
  f32x4 acc[4][4] = {};
  const int r4 = t >> 2, cb = (t & 3) * 8;
  const short* aptr = A + (brow + r4) * (long)K + cb;
  const short* bptr = Bm + (bcol + r4) * (long)K + cb;
  for (int k0 = 0; k0 < K; k0 += 32) {
    gload_lds16(aptr + k0, &As[r4 * 32 + cb]);
    gload_lds16(aptr + k0 + 64 * (long)K, &As[(r4 + 64) * 32 + cb]);
    gload_lds16(bptr + k0, &Bs[r4 * 32 + cb]);
    gload_lds16(bptr + k0 + 64 * (long)K, &Bs[(r4 + 64) * 32 + cb]);
    __syncthreads();
    short8 af[4], bfr[4];
#pragma unroll
    for (int m = 0; m < 4; ++m)
      af[m] = *(const short8*)&As[(wr * 64 + m * 16 + q) * 32 + g * 8];
#pragma unroll
    for (int n = 0; n < 4; ++n)
      bfr[n] = *(const short8*)&Bs[(wc * 64 + n * 16 + q) * 32 + g * 8];
#pragma unroll
    for (int m = 0; m < 4; ++m)
#pragma unroll
      for (int n = 0; n < 4; ++n)
        acc[m][n] = __builtin_amdgcn_mfma_f32_16x16x32_bf16(af[m], bfr[n], acc[m][n], 0, 0, 0);
    __syncthreads();
  }
#pragma unroll
  for (int m = 0; m < 4; ++m)
#pragma unroll
    for (int n = 0; n < 4; ++n)
#pragma unroll
      for (int r = 0; r < 4; ++r) {
        long row = brow + wr * 64 + m * 16 + g * 4 + r;
        long col = bcol + wc * 64 + n * 16 + q;
        float v = acc[m][n][r] + bias[col];
        if (EPI == 0) {
          if (col < 1024) v *= 0.125f;
          ((unsigned short*)Cout)[row * ldc + col] = f2bf(v);
        } else {
          ((float*)Cout)[row * ldc + col] = v;
        }
      }
}

// ---------------- flash attention ----------------
// qkv: [4096 rows][3072] bf16 (q|k|v, q pre-scaled by 1/8). z out: [4096][1024] bf16.
__global__ __launch_bounds__(256) void attn(const short* __restrict__ qkv,
                                            unsigned short* __restrict__ zb) {
  __shared__ short Ks[64 * 64];
  __shared__ short Vt[64 * 64];
  __shared__ unsigned short Ps[4 * 16 * 64];
  const int bid = blockIdx.x;
  const int qt = bid & 31, bh = bid >> 5, b = bh >> 4, h = bh & 15;
  const int t = threadIdx.x, l = t & 63, w = t >> 6;
  const int lq = l & 15, g = l >> 4;
  const long rowbase = (long)b * 2048;
  const short* qp = qkv + rowbase * 3072 + h * 64;
  const short* kp = qp + 1024;
  const short* vp = qp + 2048;
  const int qrow0 = qt * 64 + w * 16;
  short8 qf[2];
#pragma unroll
  for (int kg = 0; kg < 2; ++kg)
    qf[kg] = *(const short8*)(qp + (long)(qrow0 + lq) * 3072 + kg * 32 + g * 8);
  f32x4 zacc[4] = {};
  float mrun = -1e30f, lrun = 0.0f;
  unsigned short* Pw = Ps + w * (16 * 64);
  const int sr = t >> 3;   // 0..31
  const int sc = t & 7;    // col block

  for (int j = 0; j <= qt; ++j) {
    __syncthreads();  // previous iteration's LDS readers done
    // stage K via global_load_lds, source pre-swizzled so LDS ends up XOR-swizzled
#pragma unroll
    for (int i = 0; i < 2; ++i) {
      int r = i * 32 + sr;
      int cbk = (sc ^ (r & 7)) * 8;
      gload_lds16(kp + (long)(j * 64 + r) * 3072 + cbk, &Ks[i * 2048 + t * 8]);
    }
    // stage V via regs, transposed into Vt[dh][k] with swizzle sw(dh)=(dh&7)^((dh>>3)&7)
    short8 vv[2];
#pragma unroll
    for (int i = 0; i < 2; ++i)
      vv[i] = *(const short8*)(vp + (long)(j * 64 + i * 32 + sr) * 3072 + sc * 8);
#pragma unroll
    for (int i = 0; i < 2; ++i) {
      int r = i * 32 + sr;
      int blk = r >> 3, rl = r & 7;
#pragma unroll
      for (int idx = 0; idx < 8; ++idx) {
        int dh = sc * 8 + idx;
        int sw = (dh & 7) ^ ((dh >> 3) & 7);
        Vt[dh * 64 + ((blk ^ sw) * 8) + rl] = vv[i][idx];
      }
    }
    __syncthreads();
    // S^T[k][q] = K · Q^T
    f32x4 sacc[4] = {};
#pragma unroll
    for (int m = 0; m < 4; ++m) {
#pragma unroll
      for (int kg = 0; kg < 2; ++kg) {
        int krow = m * 16 + lq;
        int blk = kg * 4 + g;
        short8 kf = *(const short8*)&Ks[krow * 64 + (blk ^ (krow & 7)) * 8];
        sacc[m] = __builtin_amdgcn_mfma_f32_16x16x32_bf16(kf, qf[kg], sacc[m], 0, 0, 0);
      }
    }
    if (j == qt) {
      // causal mask: key_local > (wave's q-row offset) + lq  [FIX: w*16 term]
#pragma unroll
      for (int m = 0; m < 4; ++m)
#pragma unroll
        for (int r = 0; r < 4; ++r)
          if (m * 16 + g * 4 + r > w * 16 + lq) sacc[m][r] = -1e30f;
    }
    // online softmax per column (q = lq); reduce across the 4 lane-groups
    float tmax = -1e30f;
#pragma unroll
    for (int m = 0; m < 4; ++m)
#pragma unroll
      for (int r = 0; r < 4; ++r) tmax = fmaxf(tmax, sacc[m][r]);
    tmax = fmaxf(tmax, __shfl_xor(tmax, 16));
    tmax = fmaxf(tmax, __shfl_xor(tmax, 32));
    float mnew = fmaxf(mrun, tmax);
    float alpha = __expf(mrun - mnew);
    float p[4][4];
    float tsum = 0.f;
#pragma unroll
    for (int m = 0; m < 4; ++m)
#pragma unroll
      for (int r = 0; r < 4; ++r) {
        float e = __expf(sacc[m][r] - mnew);
        p[m][r] = e;
        tsum += e;
      }
    tsum += __shfl_xor(tsum, 16);
    tsum += __shfl_xor(tsum, 32);
    lrun = lrun * alpha + tsum;
    mrun = mnew;
#pragma unroll
    for (int r = 0; r < 4; ++r) {
      float ar = __shfl(alpha, g * 4 + r);
#pragma unroll
      for (int n2 = 0; n2 < 4; ++n2) zacc[n2][r] *= ar;
    }
    // write P[q][k] to per-wave LDS (8B chunks, XOR-swizzled by q)
#pragma unroll
    for (int m = 0; m < 4; ++m) {
      ushort4v pk;
      pk[0] = f2bf(p[m][0]); pk[1] = f2bf(p[m][1]);
      pk[2] = f2bf(p[m][2]); pk[3] = f2bf(p[m][3]);
      int c = m * 4 + g;
      int csw = c ^ ((lq & 7) << 1);
      *(ushort4v*)&Pw[lq * 64 + csw * 4] = pk;
    }
    // PV: Z[q][dh] += P · V
    short8 pf[2];
#pragma unroll
    for (int kg2 = 0; kg2 < 2; ++kg2) {
      int c0 = kg2 * 8 + g * 2;
      int c0s = c0 ^ ((lq & 7) << 1);
      pf[kg2] = *(const short8*)&Pw[lq * 64 + c0s * 4];
    }
#pragma unroll
    for (int n2 = 0; n2 < 4; ++n2) {
#pragma unroll
      for (int kg2 = 0; kg2 < 2; ++kg2) {
        int dh = n2 * 16 + lq;
        int sw = (dh & 7) ^ ((dh >> 3) & 7);
        int blk = kg2 * 4 + g;
        short8 vf = *(const short8*)&Vt[dh * 64 + ((blk ^ sw) * 8)];
        zacc[n2] = __builtin_amdgcn_mfma_f32_16x16x32_bf16(pf[kg2], vf, zacc[n2], 0, 0, 0);
      }
    }
  }
  // normalize + write z (bf16)
#pragma unroll
  for (int r = 0; r < 4; ++r) {
    float linv = 1.0f / __shfl(lrun, g * 4 + r);
    long grow = rowbase + qt * 64 + w * 16 + g * 4 + r;
#pragma unroll
    for (int n2 = 0; n2 < 4; ++n2) {
      int col = h * 64 + n2 * 16 + lq;
      zb[grow * 1024 + col] = f2bf(zacc[n2][r] * linv);
    }
  }
}

extern "C" void kernel_launch(void* const* d_in, const int* in_sizes, int n_in,
                              void* d_out, int out_size, void* d_ws, size_t ws_size,
                              hipStream_t stream) {
  const float* x  = (const float*)d_in[0];
  const float* wq = (const float*)d_in[1];
  const float* wk = (const float*)d_in[2];
  const float* wv = (const float*)d_in[3];
  const float* wo = (const float*)d_in[4];
  const float* bq = (const float*)d_in[5];
  const float* bk = (const float*)d_in[6];
  const float* bv = (const float*)d_in[7];
  const float* bo = (const float*)d_in[8];
  char* ws = (char*)d_ws;
  if (ws_size < ((size_t)48 * 1024 * 1024 + 16384)) return;  // need ~48MB
  short*          xb    = (short*)(ws);                         //  8 MB
  short*          qkvb  = (short*)(ws + ((size_t)8  << 20));    // 24 MB
  unsigned short* zbuf  = (unsigned short*)(ws + ((size_t)32 << 20)); // 8 MB
  short*          wqkvb = (short*)(ws + ((size_t)40 << 20));    //  6 MB
  short*          mob   = (short*)(ws + ((size_t)46 << 20));    //  2 MB
  float*          bqkv  = (float*)(ws + ((size_t)48 << 20));    // 12 KB

  cast_x_k   <<<4096, 256, 0, stream>>>(x, xb);
  cast_wqkv_k<<<3072, 256, 0, stream>>>(wq, wk, wv, wqkvb);
  cast_wo_k  <<<1024, 256, 0, stream>>>(wo, mob);
  bias_k     <<<12,   256, 0, stream>>>(bq, bk, bv, bqkv);

  gemm_bt<0><<<dim3(24, 32), 256, 0, stream>>>(xb, wqkvb, bqkv, (void*)qkvb, 1024, 3072);
  attn      <<<1024,         256, 0, stream>>>(qkvb, zbuf);
  gemm_bt<1><<<dim3(8, 32),  256, 0, stream>>>((const short*)zbuf, mob, bo, d_out, 1024, 1024);
}

// Round 3
// 137.414 us; speedup vs baseline: 1.3179x; 1.3179x over previous
//
#include <hip/hip_runtime.h>
#include <stdint.h>

typedef __attribute__((ext_vector_type(8))) short short8;
typedef __attribute__((ext_vector_type(4))) short short4v;
typedef __attribute__((ext_vector_type(4))) float f32x4;
typedef __attribute__((ext_vector_type(4))) unsigned short ushort4v;

#define AS1(p) ((const __attribute__((address_space(1))) void*)(p))
#define AS3(p) ((__attribute__((address_space(3))) void*)(p))

__device__ __forceinline__ void gload_lds16(const void* g, void* l) {
  __builtin_amdgcn_global_load_lds(AS1(g), AS3(l), 16, 0, 0);
}

__device__ __forceinline__ unsigned short f2bf(float f) {
  union { float f; uint32_t u; } x; x.f = f;
  uint32_t r = x.u + 0x7FFFu + ((x.u >> 16) & 1u);
  return (unsigned short)(r >> 16);
}

// ---------------- cast kernels ----------------
__global__ void cast_x_k(const float* __restrict__ in, short* __restrict__ out) {
  int i = blockIdx.x * 256 + threadIdx.x;           // float4 index
  float4 v = ((const float4*)in)[i];
  short4v o;
  o[0] = (short)f2bf(v.x); o[1] = (short)f2bf(v.y);
  o[2] = (short)f2bf(v.z); o[3] = (short)f2bf(v.w);
  ((short4v*)out)[i] = o;
}

__global__ void cast_wqkv_k(const float* __restrict__ wq, const float* __restrict__ wk,
                            const float* __restrict__ wv, short* __restrict__ out) {
  int i = blockIdx.x * 256 + threadIdx.x;           // float4 index, 0..786431
  int e = i * 4;
  const float* src = (e < (1 << 20)) ? (wq + e)
                   : (e < (2 << 20)) ? (wk + (e - (1 << 20)))
                                     : (wv + (e - (2 << 20)));
  float4 v = *(const float4*)src;
  short4v o;
  o[0] = (short)f2bf(v.x); o[1] = (short)f2bf(v.y);
  o[2] = (short)f2bf(v.z); o[3] = (short)f2bf(v.w);
  ((short4v*)out)[i] = o;
}

__global__ void cast_wo_k(const float* __restrict__ wo, short* __restrict__ out) {
  int i = blockIdx.x * 256 + threadIdx.x;           // 0..262143
  int o4 = i * 4;
  int d = o4 >> 10, c = o4 & 1023;
  const float* s = wo + ((c >> 6) << 16) + (d << 6) + (c & 63);
  float4 v = *(const float4*)s;
  short4v o;
  o[0] = (short)f2bf(v.x); o[1] = (short)f2bf(v.y);
  o[2] = (short)f2bf(v.z); o[3] = (short)f2bf(v.w);
  ((short4v*)out)[i] = o;
}

__global__ void bias_k(const float* __restrict__ bq, const float* __restrict__ bk,
                       const float* __restrict__ bv, float* __restrict__ out) {
  int i = blockIdx.x * 256 + threadIdx.x;           // 0..3071
  out[i] = (i < 1024) ? bq[i] : (i < 2048) ? bk[i - 1024] : bv[i - 2048];
}

// ---------------- GEMM: C[M,N] = A[M,K] * B^T (B stored [N][K]) + bias ----------------
template <int EPI>
__global__ __launch_bounds__(256) void gemm_bt(const short* __restrict__ A,
                                               const short* __restrict__ Bm,
                                               const float* __restrict__ bias,
                                               void* __restrict__ Cout, int K, int ldc) {
  __shared__ short As[128 * 32];
  __shared__ short Bs[128 * 32];
  const int t = threadIdx.x;
  const int l = t & 63, w = t >> 6;
  const int wr = w >> 1, wc = w & 1;
  const int q = l & 15, g = l >> 4;
  const long brow = (long)blockIdx.y * 128;
  const long bcol = (long)blockIdx.x * 128;
  f32x4 acc[4][4] = {};
  const int r4 = t >> 2, cb = (t & 3) * 8;
  const short* aptr = A + (brow + r4) * (long)K + cb;
  const short* bptr = Bm + (bcol + r4) * (long)K + cb;
  for (int k0 = 0; k0 < K; k0 += 32) {
    gload_lds16(aptr + k0, &As[r4 * 32 + cb]);
    gload_lds16(aptr + k0 + 64 * (long)K, &As[(r4 + 64) * 32 + cb]);
    gload_lds16(bptr + k0, &Bs[r4 * 32 + cb]);
    gload_lds16(bptr + k0 + 64 * (long)K, &Bs[(r4 + 64) * 32 + cb]);
    __syncthreads();
    short8 af[4], bfr[4];
#pragma unroll
    for (int m = 0; m < 4; ++m)
      af[m] = *(const short8*)&As[(wr * 64 + m * 16 + q) * 32 + g * 8];
#pragma unroll
    for (int n = 0; n < 4; ++n)
      bfr[n] = *(const short8*)&Bs[(wc * 64 + n * 16 + q) * 32 + g * 8];
#pragma unroll
    for (int m = 0; m < 4; ++m)
#pragma unroll
      for (int n = 0; n < 4; ++n)
        acc[m][n] = __builtin_amdgcn_mfma_f32_16x16x32_bf16(af[m], bfr[n], acc[m][n], 0, 0, 0);
    __syncthreads();
  }
#pragma unroll
  for (int m = 0; m < 4; ++m)
#pragma unroll
    for (int n = 0; n < 4; ++n)
#pragma unroll
      for (int r = 0; r < 4; ++r) {
        long row = brow + wr * 64 + m * 16 + g * 4 + r;
        long col = bcol + wc * 64 + n * 16 + q;
        float v = acc[m][n][r] + bias[col];
        if (EPI == 0) {
          if (col < 1024) v *= 0.125f;
          ((unsigned short*)Cout)[row * ldc + col] = f2bf(v);
        } else {
          ((float*)Cout)[row * ldc + col] = v;
        }
      }
}

// ---------------- flash attention (paired q-tiles, double-buffered staging) ----------------
// qkv: [4096 rows][3072] bf16 (q|k|v, q pre-scaled by 1/8). z out: [4096][1024] bf16.
// 512 blocks: bid -> (xcd-grouped bh, pair). Block handles q-tiles qtA=31-pr and qtB=pr:
// (qtA+1)+(qtB+1) = 33 iterations, uniform across all blocks.
__global__ __launch_bounds__(256) void attn(const short* __restrict__ qkv,
                                            unsigned short* __restrict__ zb) {
  __shared__ short Ks[2][64 * 64];
  __shared__ short Vt[2][64 * 64];
  __shared__ unsigned short Ps[4 * 16 * 64];
  const int bid = blockIdx.x;
  const int bh = (bid & 7) * 4 + ((bid >> 3) & 3);  // 4 heads per XCD slot (L2 reuse)
  const int pr = bid >> 5;                          // 0..15
  const int qtA = 31 - pr, qtB = pr;
  const int b = bh >> 4, h = bh & 15;
  const int t = threadIdx.x, l = t & 63, w = t >> 6;
  const int lq = l & 15, g = l >> 4;
  const int u = t >> 3, c8 = t & 7;                 // staging coords
  const long rowbase = (long)b * 2048;
  const short* qp = qkv + rowbase * 3072 + h * 64;
  const short* kp = qp + 1024;
  const short* vp = qp + 2048;

  short8 qfA[2], qfB[2];
#pragma unroll
  for (int kg = 0; kg < 2; ++kg) {
    qfA[kg] = *(const short8*)(qp + (long)(qtA * 64 + w * 16 + lq) * 3072 + kg * 32 + g * 8);
    qfB[kg] = *(const short8*)(qp + (long)(qtB * 64 + w * 16 + lq) * 3072 + kg * 32 + g * 8);
  }
  f32x4 zA[4] = {}, zB[4] = {};
  float mA = -1e30f, lA = 0.0f, mB = -1e30f, lB = 0.0f;
  unsigned short* Pw = Ps + w * (16 * 64);

  // one attention step over the KV tile in buffer (ksb, vtb)
  auto step = [&](const short* ksb, const short* vtb, f32x4 (&zacc)[4],
                  float& mrun, float& lrun, short8 (&qf)[2], bool diag) {
    f32x4 sacc[4] = {};
#pragma unroll
    for (int m = 0; m < 4; ++m) {
#pragma unroll
      for (int kg = 0; kg < 2; ++kg) {
        int krow = m * 16 + lq;
        int blk = kg * 4 + g;
        short8 kf = *(const short8*)&ksb[krow * 64 + (blk ^ (krow & 7)) * 8];
        sacc[m] = __builtin_amdgcn_mfma_f32_16x16x32_bf16(kf, qf[kg], sacc[m], 0, 0, 0);
      }
    }
    if (diag) {
#pragma unroll
      for (int m = 0; m < 4; ++m)
#pragma unroll
        for (int r = 0; r < 4; ++r)
          if (m * 16 + g * 4 + r > w * 16 + lq) sacc[m][r] = -1e30f;
    }
    float tmax = -1e30f;
#pragma unroll
    for (int m = 0; m < 4; ++m)
#pragma unroll
      for (int r = 0; r < 4; ++r) tmax = fmaxf(tmax, sacc[m][r]);
    tmax = fmaxf(tmax, __shfl_xor(tmax, 16));
    tmax = fmaxf(tmax, __shfl_xor(tmax, 32));
    float mnew = fmaxf(mrun, tmax);
    float alpha = __expf(mrun - mnew);
    float p[4][4];
    float tsum = 0.f;
#pragma unroll
    for (int m = 0; m < 4; ++m)
#pragma unroll
      for (int r = 0; r < 4; ++r) {
        float e = __expf(sacc[m][r] - mnew);
        p[m][r] = e;
        tsum += e;
      }
    tsum += __shfl_xor(tsum, 16);
    tsum += __shfl_xor(tsum, 32);
    lrun = lrun * alpha + tsum;
    mrun = mnew;
#pragma unroll
    for (int r = 0; r < 4; ++r) {
      float ar = __shfl(alpha, g * 4 + r);
#pragma unroll
      for (int n2 = 0; n2 < 4; ++n2) zacc[n2][r] *= ar;
    }
#pragma unroll
    for (int m = 0; m < 4; ++m) {
      ushort4v pk;
      pk[0] = f2bf(p[m][0]); pk[1] = f2bf(p[m][1]);
      pk[2] = f2bf(p[m][2]); pk[3] = f2bf(p[m][3]);
      int c = m * 4 + g;
      int csw = c ^ ((lq & 7) << 1);
      *(ushort4v*)&Pw[lq * 64 + csw * 4] = pk;
    }
    short8 pf[2];
#pragma unroll
    for (int kg2 = 0; kg2 < 2; ++kg2) {
      int c0 = kg2 * 8 + g * 2;
      int c0s = c0 ^ ((lq & 7) << 1);
      pf[kg2] = *(const short8*)&Pw[lq * 64 + c0s * 4];
    }
#pragma unroll
    for (int n2 = 0; n2 < 4; ++n2) {
#pragma unroll
      for (int kg2 = 0; kg2 < 2; ++kg2) {
        int dh = n2 * 16 + lq;
        int sw = (dh & 7) ^ ((dh >> 3) & 7);
        int blk = kg2 * 4 + g;
        short8 vf = *(const short8*)&vtb[dh * 64 + ((blk ^ sw) * 8)];
        zacc[n2] = __builtin_amdgcn_mfma_f32_16x16x32_bf16(pf[kg2], vf, zacc[n2], 0, 0, 0);
      }
    }
  };

  // prologue: issue staging for kv tile 0 into buffer 0
  short8 va0, va1;
  {
#pragma unroll
    for (int i = 0; i < 2; ++i) {
      int r = i * 32 + u;
      int cbk = (c8 ^ (r & 7)) * 8;
      gload_lds16(kp + (long)r * 3072 + cbk, &Ks[0][i * 2048 + t * 8]);
    }
    const short* vrow = vp + (long)(2 * u) * 3072 + c8 * 8;
    va0 = *(const short8*)vrow;
    va1 = *(const short8*)(vrow + 3072);
  }

  for (int j2 = 0; j2 <= 32; ++j2) {
    const int cb = j2 & 1;
    const bool isA = (j2 <= qtA);
    const int j2n = j2 + 1;
    const int kvn = (j2n <= qtA) ? j2n : (j2n - qtA - 1);  // next kv tile index
    // K(j2) -> Ks[cb], V(j2) -> va regs: wait for them
    asm volatile("s_waitcnt vmcnt(0)" ::: "memory");
    __builtin_amdgcn_sched_barrier(0);
    __builtin_amdgcn_s_barrier();   // all waves' K(j2) complete; prev readers of cb^1 done
    // write V regs -> Vt[cb] (paired b32 writes, 2-way max)
    {
      int blk = u >> 2, rl = (u & 3) * 2;
#pragma unroll
      for (int idx = 0; idx < 8; ++idx) {
        int dh = c8 * 8 + idx;
        int sw = (dh & 7) ^ ((dh >> 3) & 7);
        uint32_t pk = (uint32_t)(uint16_t)va0[idx] | ((uint32_t)(uint16_t)va1[idx] << 16);
        *(uint32_t*)&Vt[cb][dh * 64 + ((blk ^ sw) * 8) + rl] = pk;
      }
    }
    if (j2 < 32) {
      // prefetch next KV tile into the other buffer / regs (hidden under compute)
#pragma unroll
      for (int i = 0; i < 2; ++i) {
        int r = i * 32 + u;
        int cbk = (c8 ^ (r & 7)) * 8;
        gload_lds16(kp + (long)(kvn * 64 + r) * 3072 + cbk, &Ks[cb ^ 1][i * 2048 + t * 8]);
      }
      const short* vrow = vp + (long)(kvn * 64 + 2 * u) * 3072 + c8 * 8;
      va0 = *(const short8*)vrow;
      va1 = *(const short8*)(vrow + 3072);
    }
    asm volatile("s_waitcnt lgkmcnt(0)" ::: "memory");  // Vt writes visible
    __builtin_amdgcn_sched_barrier(0);
    __builtin_amdgcn_s_barrier();
    if (isA) step(&Ks[cb][0], &Vt[cb][0], zA, mA, lA, qfA, j2 == qtA);
    else     step(&Ks[cb][0], &Vt[cb][0], zB, mB, lB, qfB, j2 == 32);
  }

  auto wout = [&](f32x4 (&zacc)[4], float lrun, int qt) {
#pragma unroll
    for (int r = 0; r < 4; ++r) {
      float linv = 1.0f / __shfl(lrun, g * 4 + r);
      long grow = rowbase + qt * 64 + w * 16 + g * 4 + r;
#pragma unroll
      for (int n2 = 0; n2 < 4; ++n2) {
        int col = h * 64 + n2 * 16 + lq;
        zb[grow * 1024 + col] = f2bf(zacc[n2][r] * linv);
      }
    }
  };
  wout(zA, lA, qtA);
  wout(zB, lB, qtB);
}

extern "C" void kernel_launch(void* const* d_in, const int* in_sizes, int n_in,
                              void* d_out, int out_size, void* d_ws, size_t ws_size,
                              hipStream_t stream) {
  const float* x  = (const float*)d_in[0];
  const float* wq = (const float*)d_in[1];
  const float* wk = (const float*)d_in[2];
  const float* wv = (const float*)d_in[3];
  const float* wo = (const float*)d_in[4];
  const float* bq = (const float*)d_in[5];
  const float* bk = (const float*)d_in[6];
  const float* bv = (const float*)d_in[7];
  const float* bo = (const float*)d_in[8];
  char* ws = (char*)d_ws;
  if (ws_size < ((size_t)48 * 1024 * 1024 + 16384)) return;  // need ~48MB
  short*          xb    = (short*)(ws);                         //  8 MB
  short*          qkvb  = (short*)(ws + ((size_t)8  << 20));    // 24 MB
  unsigned short* zbuf  = (unsigned short*)(ws + ((size_t)32 << 20)); // 8 MB
  short*          wqkvb = (short*)(ws + ((size_t)40 << 20));    //  6 MB
  short*          mob   = (short*)(ws + ((size_t)46 << 20));    //  2 MB
  float*          bqkv  = (float*)(ws + ((size_t)48 << 20));    // 12 KB

  cast_x_k   <<<4096, 256, 0, stream>>>(x, xb);
  cast_wqkv_k<<<3072, 256, 0, stream>>>(wq, wk, wv, wqkvb);
  cast_wo_k  <<<1024, 256, 0, stream>>>(wo, mob);
  bias_k     <<<12,   256, 0, stream>>>(bq, bk, bv, bqkv);

  gemm_bt<0><<<dim3(24, 32), 256, 0, stream>>>(xb, wqkvb, bqkv, (void*)qkvb, 1024, 3072);
  attn      <<<512,          256, 0, stream>>>(qkvb, zbuf);
  gemm_bt<1><<<dim3(8, 32),  256, 0, stream>>>((const short*)zbuf, mob, bo, d_out, 1024, 1024);
}

// Round 4
// 136.073 us; speedup vs baseline: 1.3309x; 1.0099x over previous
//
#include <hip/hip_runtime.h>
#include <stdint.h>

typedef __attribute__((ext_vector_type(8))) short short8;
typedef __attribute__((ext_vector_type(4))) float f32x4;

#define AS1(p) ((const __attribute__((address_space(1))) void*)(p))
#define AS3(p) ((__attribute__((address_space(3))) void*)(p))

__device__ __forceinline__ void gload_lds16(const void* g, void* l) {
  __builtin_amdgcn_global_load_lds(AS1(g), AS3(l), 16, 0, 0);
}

__device__ __forceinline__ uint32_t cvtpk_bf16(float a, float b) {
  uint32_t d;
  asm("v_cvt_pk_bf16_f32 %0, %1, %2" : "=v"(d) : "v"(a), "v"(b));
  return d;
}

__device__ __forceinline__ float fast_exp2(float x) {
#if __has_builtin(__builtin_amdgcn_exp2f)
  return __builtin_amdgcn_exp2f(x);
#else
  return exp2f(x);
#endif
}

// Q pre-scale: 1/sqrt(64) * log2(e)  (exp2-based softmax)
#define QSCALE 0.1803368801111244f

// ---------------- cast kernels ----------------
__global__ void cast_x_k(const float* __restrict__ in, uint2* __restrict__ out) {
  int i = blockIdx.x * 256 + threadIdx.x;           // float4 index
  float4 v = ((const float4*)in)[i];
  uint2 o;
  o.x = cvtpk_bf16(v.x, v.y);
  o.y = cvtpk_bf16(v.z, v.w);
  out[i] = o;
}

__global__ void cast_wqkv_k(const float* __restrict__ wq, const float* __restrict__ wk,
                            const float* __restrict__ wv, uint2* __restrict__ out) {
  int i = blockIdx.x * 256 + threadIdx.x;           // float4 index, 0..786431
  int e = i * 4;
  const float* src = (e < (1 << 20)) ? (wq + e)
                   : (e < (2 << 20)) ? (wk + (e - (1 << 20)))
                                     : (wv + (e - (2 << 20)));
  float4 v = *(const float4*)src;
  uint2 o;
  o.x = cvtpk_bf16(v.x, v.y);
  o.y = cvtpk_bf16(v.z, v.w);
  out[i] = o;
}

__global__ void cast_wo_k(const float* __restrict__ wo, uint2* __restrict__ out) {
  int i = blockIdx.x * 256 + threadIdx.x;           // 0..262143
  int o4 = i * 4;
  int d = o4 >> 10, c = o4 & 1023;
  const float* s = wo + ((c >> 6) << 16) + (d << 6) + (c & 63);
  float4 v = *(const float4*)s;
  uint2 o;
  o.x = cvtpk_bf16(v.x, v.y);
  o.y = cvtpk_bf16(v.z, v.w);
  out[i] = o;
}

__global__ void bias_k(const float* __restrict__ bq, const float* __restrict__ bk,
                       const float* __restrict__ bv, float* __restrict__ out) {
  int i = blockIdx.x * 256 + threadIdx.x;           // 0..3071
  out[i] = (i < 1024) ? bq[i] : (i < 2048) ? bk[i - 1024] : bv[i - 2048];
}

// ---------------- GEMM: C[M,N] = A[M,K] * B^T (B stored [N][K]) + bias ----------------
template <int EPI>
__global__ __launch_bounds__(256) void gemm_bt(const short* __restrict__ A,
                                               const short* __restrict__ Bm,
                                               const float* __restrict__ bias,
                                               void* __restrict__ Cout, int K, int ldc) {
  __shared__ short As[128 * 32];
  __shared__ short Bs[128 * 32];
  const int t = threadIdx.x;
  const int l = t & 63, w = t >> 6;
  const int wr = w >> 1, wc = w & 1;
  const int q = l & 15, g = l >> 4;
  const long brow = (long)blockIdx.y * 128;
  const long bcol = (long)blockIdx.x * 128;
  f32x4 acc[4][4] = {};
  const int r4 = t >> 2, cb = (t & 3) * 8;
  const short* aptr = A + (brow + r4) * (long)K + cb;
  const short* bptr = Bm + (bcol + r4) * (long)K + cb;
  for (int k0 = 0; k0 < K; k0 += 32) {
    gload_lds16(aptr + k0, &As[r4 * 32 + cb]);
    gload_lds16(aptr + k0 + 64 * (long)K, &As[(r4 + 64) * 32 + cb]);
    gload_lds16(bptr + k0, &Bs[r4 * 32 + cb]);
    gload_lds16(bptr + k0 + 64 * (long)K, &Bs[(r4 + 64) * 32 + cb]);
    __syncthreads();
    short8 af[4], bfr[4];
#pragma unroll
    for (int m = 0; m < 4; ++m)
      af[m] = *(const short8*)&As[(wr * 64 + m * 16 + q) * 32 + g * 8];
#pragma unroll
    for (int n = 0; n < 4; ++n)
      bfr[n] = *(const short8*)&Bs[(wc * 64 + n * 16 + q) * 32 + g * 8];
#pragma unroll
    for (int m = 0; m < 4; ++m)
#pragma unroll
      for (int n = 0; n < 4; ++n)
        acc[m][n] = __builtin_amdgcn_mfma_f32_16x16x32_bf16(af[m], bfr[n], acc[m][n], 0, 0, 0);
    __syncthreads();
  }
#pragma unroll
  for (int m = 0; m < 4; ++m)
#pragma unroll
    for (int n = 0; n < 4; ++n)
#pragma unroll
      for (int r = 0; r < 4; ++r) {
        long row = brow + wr * 64 + m * 16 + g * 4 + r;
        long col = bcol + wc * 64 + n * 16 + q;
        float v = acc[m][n][r] + bias[col];
        if (EPI == 0) {
          if (col < 1024) v *= QSCALE;
          ((unsigned short*)Cout)[row * ldc + col] = (unsigned short)cvtpk_bf16(v, v);
        } else {
          ((float*)Cout)[row * ldc + col] = v;
        }
      }
}

// ---------------- flash attention (paired q-tiles, double-buffered staging) ----------------
// qkv: [4096 rows][3072] bf16 (q|k|v, q pre-scaled by QSCALE). z out: [4096][1024] bf16.
__global__ __launch_bounds__(256) void attn(const short* __restrict__ qkv,
                                            unsigned short* __restrict__ zb) {
  __shared__ short Ks[2][64 * 64];
  __shared__ short Vt[2][64 * 64];
  __shared__ unsigned short Ps[4 * 16 * 64];
  const int bid = blockIdx.x;
  const int bh = (bid & 7) * 4 + ((bid >> 3) & 3);  // 4 heads per XCD slot (L2 reuse)
  const int pr = bid >> 5;                          // 0..15
  const int qtA = 31 - pr, qtB = pr;
  const int b = bh >> 4, h = bh & 15;
  const int t = threadIdx.x, l = t & 63, w = t >> 6;
  const int lq = l & 15, g = l >> 4;
  const int u = t >> 3, c8 = t & 7;                 // staging coords
  const long rowbase = (long)b * 2048;
  const short* qp = qkv + rowbase * 3072 + h * 64;
  const short* kp = qp + 1024;
  const short* vp = qp + 2048;

  short8 qfA[2], qfB[2];
#pragma unroll
  for (int kg = 0; kg < 2; ++kg) {
    qfA[kg] = *(const short8*)(qp + (long)(qtA * 64 + w * 16 + lq) * 3072 + kg * 32 + g * 8);
    qfB[kg] = *(const short8*)(qp + (long)(qtB * 64 + w * 16 + lq) * 3072 + kg * 32 + g * 8);
  }
  f32x4 zA[4] = {}, zB[4] = {};
  float mA = -1e30f, lA = 0.0f, mB = -1e30f, lB = 0.0f;
  unsigned short* Pw = Ps + w * (16 * 64);

  // one attention step over the KV tile in buffer (ksb, vtb)
  auto step = [&](const short* ksb, const short* vtb, f32x4 (&zacc)[4],
                  float& mrun, float& lrun, short8 (&qf)[2], bool diag) {
    f32x4 sacc[4] = {};
#pragma unroll
    for (int m = 0; m < 4; ++m) {
#pragma unroll
      for (int kg = 0; kg < 2; ++kg) {
        int krow = m * 16 + lq;
        int blk = kg * 4 + g;
        short8 kf = *(const short8*)&ksb[krow * 64 + (blk ^ (krow & 7)) * 8];
        sacc[m] = __builtin_amdgcn_mfma_f32_16x16x32_bf16(kf, qf[kg], sacc[m], 0, 0, 0);
      }
    }
    float pv[16];
#pragma unroll
    for (int m = 0; m < 4; ++m)
#pragma unroll
      for (int r = 0; r < 4; ++r) pv[m * 4 + r] = sacc[m][r];
    if (diag) {
#pragma unroll
      for (int m = 0; m < 4; ++m)
#pragma unroll
        for (int r = 0; r < 4; ++r)
          if (m * 16 + g * 4 + r > w * 16 + lq) pv[m * 4 + r] = -1e30f;
    }
    // tree max (depth 4)
    float red[8];
#pragma unroll
    for (int i = 0; i < 8; ++i) red[i] = fmaxf(pv[i], pv[i + 8]);
#pragma unroll
    for (int i = 0; i < 4; ++i) red[i] = fmaxf(red[i], red[i + 4]);
    float mx = fmaxf(fmaxf(red[0], red[2]), fmaxf(red[1], red[3]));
    mx = fmaxf(mx, __shfl_xor(mx, 16));
    mx = fmaxf(mx, __shfl_xor(mx, 32));
    // defer-max: only rescale when the new tile max overflows the 2^8 headroom
    if (!__all(mx <= mrun + 8.0f)) {
      float mnew = fmaxf(mrun, mx);
      float alpha = fast_exp2(mrun - mnew);
      lrun *= alpha;
#pragma unroll
      for (int r = 0; r < 4; ++r) {
        float ar = __shfl(alpha, g * 4 + r);
#pragma unroll
        for (int n2 = 0; n2 < 4; ++n2) zacc[n2][r] *= ar;
      }
      mrun = mnew;
    }
#pragma unroll
    for (int i = 0; i < 16; ++i) pv[i] = fast_exp2(pv[i] - mrun);
    // tree sum (depth 4)
    float rs[8];
#pragma unroll
    for (int i = 0; i < 8; ++i) rs[i] = pv[i] + pv[i + 8];
#pragma unroll
    for (int i = 0; i < 4; ++i) rs[i] = rs[i] + rs[i + 4];
    float ts = (rs[0] + rs[2]) + (rs[1] + rs[3]);
    ts += __shfl_xor(ts, 16);
    ts += __shfl_xor(ts, 32);
    lrun += ts;
    // pack P (cvt_pk) and store to per-wave LDS (8B chunks, XOR-swizzled by q)
#pragma unroll
    for (int m = 0; m < 4; ++m) {
      uint2 wv;
      wv.x = cvtpk_bf16(pv[m * 4 + 0], pv[m * 4 + 1]);
      wv.y = cvtpk_bf16(pv[m * 4 + 2], pv[m * 4 + 3]);
      int c = m * 4 + g;
      int csw = c ^ ((lq & 7) << 1);
      *(uint2*)&Pw[lq * 64 + csw * 4] = wv;
    }
    short8 pf[2];
#pragma unroll
    for (int kg2 = 0; kg2 < 2; ++kg2) {
      int c0 = kg2 * 8 + g * 2;
      int c0s = c0 ^ ((lq & 7) << 1);
      pf[kg2] = *(const short8*)&Pw[lq * 64 + c0s * 4];
    }
#pragma unroll
    for (int n2 = 0; n2 < 4; ++n2) {
#pragma unroll
      for (int kg2 = 0; kg2 < 2; ++kg2) {
        int dh = n2 * 16 + lq;
        int sw = (dh & 7) ^ ((dh >> 3) & 7);
        int blk = kg2 * 4 + g;
        short8 vf = *(const short8*)&vtb[dh * 64 + ((blk ^ sw) * 8)];
        zacc[n2] = __builtin_amdgcn_mfma_f32_16x16x32_bf16(pf[kg2], vf, zacc[n2], 0, 0, 0);
      }
    }
  };

  // prologue: issue staging for kv tile 0 into buffer 0
  short8 va0, va1;
  {
#pragma unroll
    for (int i = 0; i < 2; ++i) {
      int r = i * 32 + u;
      int cbk = (c8 ^ (r & 7)) * 8;
      gload_lds16(kp + (long)r * 3072 + cbk, &Ks[0][i * 2048 + t * 8]);
    }
    const short* vrow = vp + (long)(2 * u) * 3072 + c8 * 8;
    va0 = *(const short8*)vrow;
    va1 = *(const short8*)(vrow + 3072);
  }

  for (int j2 = 0; j2 <= 32; ++j2) {
    const int cb = j2 & 1;
    const bool isA = (j2 <= qtA);
    const int j2n = j2 + 1;
    const int kvn = (j2n <= qtA) ? j2n : (j2n - qtA - 1);  // next kv tile index
    asm volatile("s_waitcnt vmcnt(0)" ::: "memory");
    __builtin_amdgcn_sched_barrier(0);
    __builtin_amdgcn_s_barrier();   // all waves' K(j2) complete; prev readers of cb^1 done
    // write V regs -> Vt[cb] (paired b32 writes, 2-way max)
    {
      int blk = u >> 2, rl = (u & 3) * 2;
#pragma unroll
      for (int idx = 0; idx < 8; ++idx) {
        int dh = c8 * 8 + idx;
        int sw = (dh & 7) ^ ((dh >> 3) & 7);
        uint32_t pk = (uint32_t)(uint16_t)va0[idx] | ((uint32_t)(uint16_t)va1[idx] << 16);
        *(uint32_t*)&Vt[cb][dh * 64 + ((blk ^ sw) * 8) + rl] = pk;
      }
    }
    if (j2 < 32) {
      // prefetch next KV tile into the other buffer / regs (hidden under compute)
#pragma unroll
      for (int i = 0; i < 2; ++i) {
        int r = i * 32 + u;
        int cbk = (c8 ^ (r & 7)) * 8;
        gload_lds16(kp + (long)(kvn * 64 + r) * 3072 + cbk, &Ks[cb ^ 1][i * 2048 + t * 8]);
      }
      const short* vrow = vp + (long)(kvn * 64 + 2 * u) * 3072 + c8 * 8;
      va0 = *(const short8*)vrow;
      va1 = *(const short8*)(vrow + 3072);
    }
    asm volatile("s_waitcnt lgkmcnt(0)" ::: "memory");  // Vt writes visible
    __builtin_amdgcn_sched_barrier(0);
    __builtin_amdgcn_s_barrier();
    if (isA) step(&Ks[cb][0], &Vt[cb][0], zA, mA, lA, qfA, j2 == qtA);
    else     step(&Ks[cb][0], &Vt[cb][0], zB, mB, lB, qfB, j2 == 32);
  }

  auto wout = [&](f32x4 (&zacc)[4], float lrun, int qt) {
#pragma unroll
    for (int r = 0; r < 4; ++r) {
      float linv = 1.0f / __shfl(lrun, g * 4 + r);
      long grow = rowbase + qt * 64 + w * 16 + g * 4 + r;
#pragma unroll
      for (int n2 = 0; n2 < 4; ++n2) {
        int col = h * 64 + n2 * 16 + lq;
        float zv = zacc[n2][r] * linv;
        zb[grow * 1024 + col] = (unsigned short)cvtpk_bf16(zv, zv);
      }
    }
  };
  wout(zA, lA, qtA);
  wout(zB, lB, qtB);
}

extern "C" void kernel_launch(void* const* d_in, const int* in_sizes, int n_in,
                              void* d_out, int out_size, void* d_ws, size_t ws_size,
                              hipStream_t stream) {
  const float* x  = (const float*)d_in[0];
  const float* wq = (const float*)d_in[1];
  const float* wk = (const float*)d_in[2];
  const float* wv = (const float*)d_in[3];
  const float* wo = (const float*)d_in[4];
  const float* bq = (const float*)d_in[5];
  const float* bk = (const float*)d_in[6];
  const float* bv = (const float*)d_in[7];
  const float* bo = (const float*)d_in[8];
  char* ws = (char*)d_ws;
  if (ws_size < ((size_t)48 * 1024 * 1024 + 16384)) return;  // need ~48MB
  short*          xb    = (short*)(ws);                         //  8 MB
  short*          qkvb  = (short*)(ws + ((size_t)8  << 20));    // 24 MB
  unsigned short* zbuf  = (unsigned short*)(ws + ((size_t)32 << 20)); // 8 MB
  short*          wqkvb = (short*)(ws + ((size_t)40 << 20));    //  6 MB
  short*          mob   = (short*)(ws + ((size_t)46 << 20));    //  2 MB
  float*          bqkv  = (float*)(ws + ((size_t)48 << 20));    // 12 KB

  cast_x_k   <<<4096, 256, 0, stream>>>(x, (uint2*)xb);
  cast_wqkv_k<<<3072, 256, 0, stream>>>(wq, wk, wv, (uint2*)wqkvb);
  cast_wo_k  <<<1024, 256, 0, stream>>>(wo, (uint2*)mob);
  bias_k     <<<12,   256, 0, stream>>>(bq, bk, bv, bqkv);

  gemm_bt<0><<<dim3(24, 32), 256, 0, stream>>>(xb, wqkvb, bqkv, (void*)qkvb, 1024, 3072);
  attn      <<<512,          256, 0, stream>>>(qkvb, zbuf);
  gemm_bt<1><<<dim3(8, 32),  256, 0, stream>>>((const short*)zbuf, mob, bo, d_out, 1024, 1024);
}

// Round 5
// 134.488 us; speedup vs baseline: 1.3466x; 1.0118x over previous
//
#include <hip/hip_runtime.h>
#include <stdint.h>

typedef __attribute__((ext_vector_type(8))) short short8;
typedef __attribute__((ext_vector_type(4))) float f32x4;

#define AS1(p) ((const __attribute__((address_space(1))) void*)(p))
#define AS3(p) ((__attribute__((address_space(3))) void*)(p))

__device__ __forceinline__ void gload_lds16(const void* g, void* l) {
  __builtin_amdgcn_global_load_lds(AS1(g), AS3(l), 16, 0, 0);
}

__device__ __forceinline__ uint32_t cvtpk_bf16(float a, float b) {
  uint32_t d;
  asm("v_cvt_pk_bf16_f32 %0, %1, %2" : "=v"(d) : "v"(a), "v"(b));
  return d;
}

__device__ __forceinline__ float fast_exp2(float x) {
#if __has_builtin(__builtin_amdgcn_exp2f)
  return __builtin_amdgcn_exp2f(x);
#else
  return exp2f(x);
#endif
}

// Q pre-scale: 1/sqrt(64) * log2(e)  (exp2-based softmax)
#define QSCALE 0.1803368801111244f

// ---------------- cast kernels ----------------
__global__ void cast_x_k(const float* __restrict__ in, uint2* __restrict__ out) {
  int i = blockIdx.x * 256 + threadIdx.x;           // float4 index
  float4 v = ((const float4*)in)[i];
  uint2 o;
  o.x = cvtpk_bf16(v.x, v.y);
  o.y = cvtpk_bf16(v.z, v.w);
  out[i] = o;
}

__global__ void cast_wqkv_k(const float* __restrict__ wq, const float* __restrict__ wk,
                            const float* __restrict__ wv, uint2* __restrict__ out) {
  int i = blockIdx.x * 256 + threadIdx.x;           // float4 index, 0..786431
  int e = i * 4;
  const float* src = (e < (1 << 20)) ? (wq + e)
                   : (e < (2 << 20)) ? (wk + (e - (1 << 20)))
                                     : (wv + (e - (2 << 20)));
  float4 v = *(const float4*)src;
  uint2 o;
  o.x = cvtpk_bf16(v.x, v.y);
  o.y = cvtpk_bf16(v.z, v.w);
  out[i] = o;
}

__global__ void cast_wo_k(const float* __restrict__ wo, uint2* __restrict__ out) {
  int i = blockIdx.x * 256 + threadIdx.x;           // 0..262143
  int o4 = i * 4;
  int d = o4 >> 10, c = o4 & 1023;
  const float* s = wo + ((c >> 6) << 16) + (d << 6) + (c & 63);
  float4 v = *(const float4*)s;
  uint2 o;
  o.x = cvtpk_bf16(v.x, v.y);
  o.y = cvtpk_bf16(v.z, v.w);
  out[i] = o;
}

__global__ void bias_k(const float* __restrict__ bq, const float* __restrict__ bk,
                       const float* __restrict__ bv, float* __restrict__ out) {
  int i = blockIdx.x * 256 + threadIdx.x;           // 0..3071
  out[i] = (i < 1024) ? bq[i] : (i < 2048) ? bk[i - 1024] : bv[i - 2048];
}

// ---------------- GEMM: C[M,N] = A[M,K] * B^T (B stored [N][K]) + bias ----------------
template <int EPI>
__global__ __launch_bounds__(256) void gemm_bt(const short* __restrict__ A,
                                               const short* __restrict__ Bm,
                                               const float* __restrict__ bias,
                                               void* __restrict__ Cout, int K, int ldc) {
  __shared__ short As[128 * 32];
  __shared__ short Bs[128 * 32];
  const int t = threadIdx.x;
  const int l = t & 63, w = t >> 6;
  const int wr = w >> 1, wc = w & 1;
  const int q = l & 15, g = l >> 4;
  const long brow = (long)blockIdx.y * 128;
  const long bcol = (long)blockIdx.x * 128;
  f32x4 acc[4][4] = {};
  const int r4 = t >> 2, cb = (t & 3) * 8;
  const short* aptr = A + (brow + r4) * (long)K + cb;
  const short* bptr = Bm + (bcol + r4) * (long)K + cb;
  for (int k0 = 0; k0 < K; k0 += 32) {
    gload_lds16(aptr + k0, &As[r4 * 32 + cb]);
    gload_lds16(aptr + k0 + 64 * (long)K, &As[(r4 + 64) * 32 + cb]);
    gload_lds16(bptr + k0, &Bs[r4 * 32 + cb]);
    gload_lds16(bptr + k0 + 64 * (long)K, &Bs[(r4 + 64) * 32 + cb]);
    __syncthreads();
    short8 af[4], bfr[4];
#pragma unroll
    for (int m = 0; m < 4; ++m)
      af[m] = *(const short8*)&As[(wr * 64 + m * 16 + q) * 32 + g * 8];
#pragma unroll
    for (int n = 0; n < 4; ++n)
      bfr[n] = *(const short8*)&Bs[(wc * 64 + n * 16 + q) * 32 + g * 8];
#pragma unroll
    for (int m = 0; m < 4; ++m)
#pragma unroll
      for (int n = 0; n < 4; ++n)
        acc[m][n] = __builtin_amdgcn_mfma_f32_16x16x32_bf16(af[m], bfr[n], acc[m][n], 0, 0, 0);
    __syncthreads();
  }
#pragma unroll
  for (int m = 0; m < 4; ++m)
#pragma unroll
    for (int n = 0; n < 4; ++n)
#pragma unroll
      for (int r = 0; r < 4; ++r) {
        long row = brow + wr * 64 + m * 16 + g * 4 + r;
        long col = bcol + wc * 64 + n * 16 + q;
        float v = acc[m][n][r] + bias[col];
        if (EPI == 0) {
          if (col < 1024) v *= QSCALE;
          ((unsigned short*)Cout)[row * ldc + col] = (unsigned short)cvtpk_bf16(v, v);
        } else {
          ((float*)Cout)[row * ldc + col] = v;
        }
      }
}

// ---------------- flash attention ----------------
// 256 blocks x 512 threads: each block = TWO independent 4-wave units (same head,
// different q-tile pair) sharing the barrier rhythm (both run exactly 33 iters).
// 16 waves/CU. qkv: [4096][3072] bf16 (q|k|v, q pre-scaled). z: [4096][1024] bf16.
__global__ __launch_bounds__(512) void attn(const short* __restrict__ qkv,
                                            unsigned short* __restrict__ zb) {
  __shared__ short Ks[2][2][64 * 64];   // [unit][buf]
  __shared__ short Vt[2][2][64 * 64];   // [unit][buf]
  __shared__ unsigned short Ps[2][4][16 * 64];  // [unit][wave]
  const int bid = blockIdx.x;
  const int t = threadIdx.x;
  const int unit = t >> 8;                          // 0..1
  const int tu = t & 255;                           // thread-in-unit
  const int bh = (bid & 7) * 4 + ((bid >> 3) & 3);  // 4 heads per XCD slot (L2 reuse)
  const int pr = (bid >> 5) * 2 + unit;             // 0..15
  const int qtA = 31 - pr, qtB = pr;
  const int b = bh >> 4, h = bh & 15;
  const int l = tu & 63, w = tu >> 6;
  const int lq = l & 15, g = l >> 4;
  const int u = tu >> 3, c8 = tu & 7;               // staging coords (in-unit)
  const long rowbase = (long)b * 2048;
  const short* qp = qkv + rowbase * 3072 + h * 64;
  const short* kp = qp + 1024;
  const short* vp = qp + 2048;

  short8 qfA[2], qfB[2];
#pragma unroll
  for (int kg = 0; kg < 2; ++kg) {
    qfA[kg] = *(const short8*)(qp + (long)(qtA * 64 + w * 16 + lq) * 3072 + kg * 32 + g * 8);
    qfB[kg] = *(const short8*)(qp + (long)(qtB * 64 + w * 16 + lq) * 3072 + kg * 32 + g * 8);
  }
  f32x4 zA[4] = {}, zB[4] = {};
  float mA = -1e30f, lA = 0.0f, mB = -1e30f, lB = 0.0f;
  unsigned short* Pw = &Ps[unit][w][0];

  // one attention step over the KV tile in buffer (ksb, vtb)
  auto step = [&](const short* ksb, const short* vtb, f32x4 (&zacc)[4],
                  float& mrun, float& lrun, short8 (&qf)[2], bool diag) {
    f32x4 sacc[4] = {};
#pragma unroll
    for (int m = 0; m < 4; ++m) {
#pragma unroll
      for (int kg = 0; kg < 2; ++kg) {
        int krow = m * 16 + lq;
        int blk = kg * 4 + g;
        short8 kf = *(const short8*)&ksb[krow * 64 + (blk ^ (krow & 7)) * 8];
        sacc[m] = __builtin_amdgcn_mfma_f32_16x16x32_bf16(kf, qf[kg], sacc[m], 0, 0, 0);
      }
    }
    float pv[16];
#pragma unroll
    for (int m = 0; m < 4; ++m)
#pragma unroll
      for (int r = 0; r < 4; ++r) pv[m * 4 + r] = sacc[m][r];
    if (diag) {
#pragma unroll
      for (int m = 0; m < 4; ++m)
#pragma unroll
        for (int r = 0; r < 4; ++r)
          if (m * 16 + g * 4 + r > w * 16 + lq) pv[m * 4 + r] = -1e30f;
    }
    // tree max (depth 4)
    float red[8];
#pragma unroll
    for (int i = 0; i < 8; ++i) red[i] = fmaxf(pv[i], pv[i + 8]);
#pragma unroll
    for (int i = 0; i < 4; ++i) red[i] = fmaxf(red[i], red[i + 4]);
    float mx = fmaxf(fmaxf(red[0], red[2]), fmaxf(red[1], red[3]));
    mx = fmaxf(mx, __shfl_xor(mx, 16));
    mx = fmaxf(mx, __shfl_xor(mx, 32));
    // defer-max: only rescale when the new tile max overflows the 2^8 headroom
    if (!__all(mx <= mrun + 8.0f)) {
      float mnew = fmaxf(mrun, mx);
      float alpha = fast_exp2(mrun - mnew);
      lrun *= alpha;
#pragma unroll
      for (int r = 0; r < 4; ++r) {
        float ar = __shfl(alpha, g * 4 + r);
#pragma unroll
        for (int n2 = 0; n2 < 4; ++n2) zacc[n2][r] *= ar;
      }
      mrun = mnew;
    }
#pragma unroll
    for (int i = 0; i < 16; ++i) pv[i] = fast_exp2(pv[i] - mrun);
    // tree sum (depth 4)
    float rs[8];
#pragma unroll
    for (int i = 0; i < 8; ++i) rs[i] = pv[i] + pv[i + 8];
#pragma unroll
    for (int i = 0; i < 4; ++i) rs[i] = rs[i] + rs[i + 4];
    float ts = (rs[0] + rs[2]) + (rs[1] + rs[3]);
    ts += __shfl_xor(ts, 16);
    ts += __shfl_xor(ts, 32);
    lrun += ts;
    // pack P (cvt_pk) and store to per-wave LDS (8B chunks, XOR-swizzled by q)
#pragma unroll
    for (int m = 0; m < 4; ++m) {
      uint2 wv;
      wv.x = cvtpk_bf16(pv[m * 4 + 0], pv[m * 4 + 1]);
      wv.y = cvtpk_bf16(pv[m * 4 + 2], pv[m * 4 + 3]);
      int c = m * 4 + g;
      int csw = c ^ ((lq & 7) << 1);
      *(uint2*)&Pw[lq * 64 + csw * 4] = wv;
    }
    short8 pf[2];
#pragma unroll
    for (int kg2 = 0; kg2 < 2; ++kg2) {
      int c0 = kg2 * 8 + g * 2;
      int c0s = c0 ^ ((lq & 7) << 1);
      pf[kg2] = *(const short8*)&Pw[lq * 64 + c0s * 4];
    }
#pragma unroll
    for (int n2 = 0; n2 < 4; ++n2) {
#pragma unroll
      for (int kg2 = 0; kg2 < 2; ++kg2) {
        int dh = n2 * 16 + lq;
        int sw = (dh & 7) ^ ((dh >> 3) & 7);
        int blk = kg2 * 4 + g;
        short8 vf = *(const short8*)&vtb[dh * 64 + ((blk ^ sw) * 8)];
        zacc[n2] = __builtin_amdgcn_mfma_f32_16x16x32_bf16(pf[kg2], vf, zacc[n2], 0, 0, 0);
      }
    }
  };

  // prologue: issue staging for kv tile 0 into buffer 0
  short8 va0, va1;
  {
#pragma unroll
    for (int i = 0; i < 2; ++i) {
      int r = i * 32 + u;
      int cbk = (c8 ^ (r & 7)) * 8;
      gload_lds16(kp + (long)r * 3072 + cbk, &Ks[unit][0][i * 2048 + tu * 8]);
    }
    const short* vrow = vp + (long)(2 * u) * 3072 + c8 * 8;
    va0 = *(const short8*)vrow;
    va1 = *(const short8*)(vrow + 3072);
  }

  for (int j2 = 0; j2 <= 32; ++j2) {
    const int cb = j2 & 1;
    const bool isA = (j2 <= qtA);
    const int j2n = j2 + 1;
    const int kvn = (j2n <= qtA) ? j2n : (j2n - qtA - 1);  // next kv tile index
    asm volatile("s_waitcnt vmcnt(0)" ::: "memory");
    __builtin_amdgcn_sched_barrier(0);
    __builtin_amdgcn_s_barrier();   // all waves' K(j2) complete; prev readers of cb^1 done
    // write V regs -> Vt[unit][cb] (paired b32 writes, 2-way max)
    {
      int blk = u >> 2, rl = (u & 3) * 2;
#pragma unroll
      for (int idx = 0; idx < 8; ++idx) {
        int dh = c8 * 8 + idx;
        int sw = (dh & 7) ^ ((dh >> 3) & 7);
        uint32_t pk = (uint32_t)(uint16_t)va0[idx] | ((uint32_t)(uint16_t)va1[idx] << 16);
        *(uint32_t*)&Vt[unit][cb][dh * 64 + ((blk ^ sw) * 8) + rl] = pk;
      }
    }
    if (j2 < 32) {
      // prefetch next KV tile into the other buffer / regs (hidden under compute)
#pragma unroll
      for (int i = 0; i < 2; ++i) {
        int r = i * 32 + u;
        int cbk = (c8 ^ (r & 7)) * 8;
        gload_lds16(kp + (long)(kvn * 64 + r) * 3072 + cbk, &Ks[unit][cb ^ 1][i * 2048 + tu * 8]);
      }
      const short* vrow = vp + (long)(kvn * 64 + 2 * u) * 3072 + c8 * 8;
      va0 = *(const short8*)vrow;
      va1 = *(const short8*)(vrow + 3072);
    }
    asm volatile("s_waitcnt lgkmcnt(0)" ::: "memory");  // Vt writes visible
    __builtin_amdgcn_sched_barrier(0);
    __builtin_amdgcn_s_barrier();
    if (isA) step(&Ks[unit][cb][0], &Vt[unit][cb][0], zA, mA, lA, qfA, j2 == qtA);
    else     step(&Ks[unit][cb][0], &Vt[unit][cb][0], zB, mB, lB, qfB, j2 == 32);
  }

  auto wout = [&](f32x4 (&zacc)[4], float lrun, int qt) {
#pragma unroll
    for (int r = 0; r < 4; ++r) {
      float linv = 1.0f / __shfl(lrun, g * 4 + r);
      long grow = rowbase + qt * 64 + w * 16 + g * 4 + r;
#pragma unroll
      for (int n2 = 0; n2 < 4; ++n2) {
        int col = h * 64 + n2 * 16 + lq;
        float zv = zacc[n2][r] * linv;
        zb[grow * 1024 + col] = (unsigned short)cvtpk_bf16(zv, zv);
      }
    }
  };
  wout(zA, lA, qtA);
  wout(zB, lB, qtB);
}

extern "C" void kernel_launch(void* const* d_in, const int* in_sizes, int n_in,
                              void* d_out, int out_size, void* d_ws, size_t ws_size,
                              hipStream_t stream) {
  const float* x  = (const float*)d_in[0];
  const float* wq = (const float*)d_in[1];
  const float* wk = (const float*)d_in[2];
  const float* wv = (const float*)d_in[3];
  const float* wo = (const float*)d_in[4];
  const float* bq = (const float*)d_in[5];
  const float* bk = (const float*)d_in[6];
  const float* bv = (const float*)d_in[7];
  const float* bo = (const float*)d_in[8];
  char* ws = (char*)d_ws;
  if (ws_size < ((size_t)48 * 1024 * 1024 + 16384)) return;  // need ~48MB
  short*          xb    = (short*)(ws);                         //  8 MB
  short*          qkvb  = (short*)(ws + ((size_t)8  << 20));    // 24 MB
  unsigned short* zbuf  = (unsigned short*)(ws + ((size_t)32 << 20)); // 8 MB
  short*          wqkvb = (short*)(ws + ((size_t)40 << 20));    //  6 MB
  short*          mob   = (short*)(ws + ((size_t)46 << 20));    //  2 MB
  float*          bqkv  = (float*)(ws + ((size_t)48 << 20));    // 12 KB

  cast_x_k   <<<4096, 256, 0, stream>>>(x, (uint2*)xb);
  cast_wqkv_k<<<3072, 256, 0, stream>>>(wq, wk, wv, (uint2*)wqkvb);
  cast_wo_k  <<<1024, 256, 0, stream>>>(wo, (uint2*)mob);
  bias_k     <<<12,   256, 0, stream>>>(bq, bk, bv, bqkv);

  gemm_bt<0><<<dim3(24, 32), 256, 0, stream>>>(xb, wqkvb, bqkv, (void*)qkvb, 1024, 3072);
  attn      <<<256,          512, 0, stream>>>(qkvb, zbuf);
  gemm_bt<1><<<dim3(8, 32),  256, 0, stream>>>((const short*)zbuf, mob, bo, d_out, 1024, 1024);
}